// Round 7
// baseline (807.120 us; speedup 1.0000x reference)
//
#include <hip/hip_runtime.h>

// ES gradient for 2-layer MLP (D_IN=1024, HID=2048, D_OUT=10, POP=40, STD=0.1).
// k_xsplit (x -> swizzled split-f16 LDS-image) -> k_base (fp32 x@W1+b1) ->
// k_big (split-f16 MFMA x@E1 + fused layer-2 partials, j64 x b256 tiles) ->
// k_loss -> k_rank -> k_grad.
// Losses matter only through RANKS (gaps ~1e-2); split-f16 err ~1e-5 => safe.

#define NPLL 2119690LL          // N_PARAMS
#define S1_  2097152            // W1 end
#define S2_  2099200            // b1 end
#define S3_  2119680            // W2 end

// ws layout (f32 units):
//   base : [0, 524288)            base[j][b]  f32
//   ppu  : [524288, 3801088)      f16-packed [40][2][32 jt][256 b][5 dw]
//   loss : [3801088, 3801168)
//   g    : [3801168, 3801208)
//   xs   : [3801216, +262144)     f16 image [32 kt][256 b][8 chunks swizzled]
#define WS_PP   524288
#define WS_LOSS 3801088
#define WS_G    3801168
#define WS_XS   3801216

typedef _Float16 f16;
typedef __fp16   fp16x2 __attribute__((ext_vector_type(2)));
typedef _Float16 f16x8 __attribute__((ext_vector_type(8)));
typedef float    f32x4 __attribute__((ext_vector_type(4)));

__device__ __forceinline__ unsigned pk2r(float a, float b, float& ra, float& rb) {
  fp16x2 h = __builtin_amdgcn_cvt_pkrtz(a, b);
  ra = a - (float)h[0];
  rb = b - (float)h[1];
  return __builtin_bit_cast(unsigned, h);
}
__device__ __forceinline__ unsigned pk2(float a, float b) {
  fp16x2 h = __builtin_amdgcn_cvt_pkrtz(a, b);
  return __builtin_bit_cast(unsigned, h);
}
__device__ __forceinline__ unsigned packh(float a, float b) {  // RTN pack
  union { f16 h[2]; unsigned u; } v;
  v.h[0] = (f16)a; v.h[1] = (f16)b;
  return v.u;
}

// ---------------- k_xsplit: x -> swizzled split-f16 tile image --------------
// Image per kt (32 KB): row b (128 B) holds 8 chunks of 16 B; logical chunk c
// (hi k-octet c<4, lo octet c-4) lives at physical chunk c ^ (b&7).
__global__ __launch_bounds__(256) void k_xsplit(const float* __restrict__ x,
                                                f16* __restrict__ xs) {
  const int idx = blockIdx.x * 256 + threadIdx.x;  // 32768
  const int b  = idx >> 7;
  const int k8 = (idx & 127) * 8;
  const int kt = k8 >> 5;
  const int q  = (k8 & 31) >> 3;       // logical hi chunk 0..3
  float4 a0 = *(const float4*)&x[(size_t)b * 1024 + k8];
  float4 a1 = *(const float4*)&x[(size_t)b * 1024 + k8 + 4];
  float v[8] = {a0.x, a0.y, a0.z, a0.w, a1.x, a1.y, a1.z, a1.w};
  float r[8];
  uint4 H, L;
  H.x = pk2r(v[0], v[1], r[0], r[1]);
  H.y = pk2r(v[2], v[3], r[2], r[3]);
  H.z = pk2r(v[4], v[5], r[4], r[5]);
  H.w = pk2r(v[6], v[7], r[6], r[7]);
  L.x = pk2(r[0], r[1]); L.y = pk2(r[2], r[3]);
  L.z = pk2(r[4], r[5]); L.w = pk2(r[6], r[7]);
  const int pq = q ^ (b & 7);
  f16* dst = xs + (size_t)kt * 16384 + b * 64;
  *(uint4*)&dst[pq * 8] = H;
  *(uint4*)&dst[(pq ^ 4) * 8] = L;
}

// ---------------- k_base: base[j][b] = (x @ W1)[b][j] + b1[j] (fp32) --------
__global__ __launch_bounds__(256) void k_base(const float* __restrict__ x,
                                              const float* __restrict__ W1,
                                              const float* __restrict__ b1,
                                              float* __restrict__ base) {
  constexpr int STR = 72;
  __shared__ float xsm[32 * STR];
  __shared__ float es[32 * STR];
  const int t  = threadIdx.x;
  const int j0 = blockIdx.x * 64;
  const int b0 = blockIdx.y * 32;
  const int tj = t & 15;
  const int tb = t >> 4;
  float acc[4][2] = {};
  for (int k0 = 0; k0 < 1024; k0 += 32) {
    __syncthreads();
    {
      int bb = t >> 3, kq = t & 7;
      float4 v = *(const float4*)&x[(size_t)(b0 + bb) * 1024 + k0 + kq * 4];
      int kb = kq * 4;
      xsm[(kb + 0) * STR + bb] = v.x;
      xsm[(kb + 1) * STR + bb] = v.y;
      xsm[(kb + 2) * STR + bb] = v.z;
      xsm[(kb + 3) * STR + bb] = v.w;
    }
#pragma unroll
    for (int r = 0; r < 2; ++r) {
      int idx = t + r * 256;
      int k = idx >> 4, jq = idx & 15, col = jq * 4;
      float4 v = *(const float4*)&W1[(size_t)(k0 + k) * 2048 + j0 + col];
      *(float4*)&es[k * STR + col + 4 * (col >> 5)] = v;
    }
    __syncthreads();
#pragma unroll 8
    for (int k = 0; k < 32; ++k) {
      const int ce = tj * 4;
      float4 e = *(const float4*)&es[k * STR + ce + 4 * (ce >> 5)];
      float2 a = *(const float2*)&xsm[k * STR + tb * 2];
      acc[0][0] += e.x * a.x; acc[0][1] += e.x * a.y;
      acc[1][0] += e.y * a.x; acc[1][1] += e.y * a.y;
      acc[2][0] += e.z * a.x; acc[2][1] += e.z * a.y;
      acc[3][0] += e.w * a.x; acc[3][1] += e.w * a.y;
    }
  }
#pragma unroll
  for (int jj = 0; jj < 4; ++jj) {
    int j = j0 + tj * 4 + jj;
    float bv = b1[j];
    float2 o = make_float2(acc[jj][0] + bv, acc[jj][1] + bv);
    *(float2*)&base[(size_t)j * 256 + b0 + tb * 2] = o;
  }
}

// ---------------- k_big: split-f16 MFMA x@E1 + fused epilogue ---------------
// grid (32 jt, 40 p), 256 threads = 4 waves; block tile j64 x b256, each wave
// owns a 64-wide b-slice and ALL 64 j rows.
__global__ __launch_bounds__(256, 2) void k_big(const f16* __restrict__ xs,
                                                const float* __restrict__ noise,
                                                const float* __restrict__ W2,
                                                const float* __restrict__ base,
                                                unsigned* __restrict__ ppu) {
  __shared__ __align__(16) char smem[40960];
  f16* eA = (f16*)smem;            // [64 j][8 chunks swz] = 8 KB
  f16* xB = (f16*)(smem + 8192);   // [256 b][8 chunks swz] = 32 KB
  float* w2l = (float*)smem;       // epilogue overlay of eA region (5.4 KB)
  float* e2l = w2l + 640;
  float* e1l = e2l + 640;

  const int t    = threadIdx.x;
  const int jt   = blockIdx.x, p = blockIdx.y;
  const int j0   = jt * 64;
  const int wave = t >> 6, lane = t & 63;
  const int lm   = lane & 15, qh = lane >> 4;   // frag row / k-octet
  const int g4   = qh * 4;
  const int bw   = wave * 64;
  const size_t pN = (size_t)p * NPLL;
  const int srow = t & 63, sq = t >> 6;         // staging role
  const int sswz = (srow & 7) << 3;

  float ve[8];
  uint4 vx[8];
  f32x4 acc[4][4];
#pragma unroll
  for (int a = 0; a < 4; ++a)
#pragma unroll
    for (int b = 0; b < 4; ++b) acc[a][b] = (f32x4){0.f, 0.f, 0.f, 0.f};

  const float* Ebase = noise + pN + (size_t)(sq * 8) * 2048 + j0 + srow;
  const f16*   xsrc  = xs + t * 8;

  // prologue: loads for ks=0
#pragma unroll
  for (int d = 0; d < 8; ++d) ve[d] = Ebase[(size_t)d * 2048];
#pragma unroll
  for (int i = 0; i < 8; ++i) vx[i] = *(const uint4*)&xsrc[i * 2048];

  for (int ks = 0; ks < 32; ++ks) {
    __syncthreads();   // previous MFMA reads done; LDS free
    {  // stage E: convert 8 f32 -> hi/lo 16B, swizzled write
      float r0, r1, r2, r3, r4, r5, r6, r7;
      uint4 H, L;
      H.x = pk2r(ve[0], ve[1], r0, r1);
      H.y = pk2r(ve[2], ve[3], r2, r3);
      H.z = pk2r(ve[4], ve[5], r4, r5);
      H.w = pk2r(ve[6], ve[7], r6, r7);
      *(uint4*)&eA[srow * 64 + ((sq * 8) ^ sswz)] = H;
      L.x = pk2(r0, r1); L.y = pk2(r2, r3);
      L.z = pk2(r4, r5); L.w = pk2(r6, r7);
      *(uint4*)&eA[srow * 64 + (((sq + 4) * 8) ^ sswz)] = L;
    }
    // stage x: linear copy of pre-swizzled image
#pragma unroll
    for (int i = 0; i < 8; ++i) *(uint4*)&xB[t * 8 + i * 2048] = vx[i];
    // prefetch next step (completes during MFMA phase)
    if (ks < 31) {
      const float* En = Ebase + (size_t)(ks + 1) * 32 * 2048;
#pragma unroll
      for (int d = 0; d < 8; ++d) ve[d] = En[(size_t)d * 2048];
      const f16* xn = xsrc + (size_t)(ks + 1) * 16384;
#pragma unroll
      for (int i = 0; i < 8; ++i) vx[i] = *(const uint4*)&xn[i * 2048];
    }
    __syncthreads();   // tiles ready
    f16x8 Bh[4], Bl[4];
#pragma unroll
    for (int nf = 0; nf < 4; ++nf) {
      const int rb = bw + nf * 16 + lm;
      const int sw = (rb & 7) << 3;
      Bh[nf] = *(const f16x8*)&xB[rb * 64 + ((qh * 8) ^ sw)];
      Bl[nf] = *(const f16x8*)&xB[rb * 64 + (((qh + 4) * 8) ^ sw)];
    }
#pragma unroll
    for (int mf = 0; mf < 4; ++mf) {
      const int ra = mf * 16 + lm;
      const int sw = (ra & 7) << 3;
      f16x8 Ah = *(const f16x8*)&eA[ra * 64 + ((qh * 8) ^ sw)];
      f16x8 Al = *(const f16x8*)&eA[ra * 64 + (((qh + 4) * 8) ^ sw)];
#pragma unroll
      for (int nf = 0; nf < 4; ++nf) {
        acc[mf][nf] = __builtin_amdgcn_mfma_f32_16x16x32_f16(Ah, Bh[nf], acc[mf][nf], 0, 0, 0);
        acc[mf][nf] = __builtin_amdgcn_mfma_f32_16x16x32_f16(Ah, Bl[nf], acc[mf][nf], 0, 0, 0);
        acc[mf][nf] = __builtin_amdgcn_mfma_f32_16x16x32_f16(Al, Bh[nf], acc[mf][nf], 0, 0, 0);
      }
    }
  }

  // ---- epilogue: tables overlay dead eA region ----
  __syncthreads();
  for (int i = t; i < 640; i += 256) {
    w2l[i] = W2[j0 * 10 + i];
    e2l[i] = noise[pN + S2_ + (size_t)j0 * 10 + i];
  }
  if (t < 64) e1l[t] = noise[pN + S1_ + j0 + t];
  __syncthreads();

#pragma unroll 1
  for (int s = 0; s < 2; ++s) {
    const float sf = s ? -0.1f : 0.1f;
    float ppv[4][10];
#pragma unroll
    for (int nf = 0; nf < 4; ++nf)
#pragma unroll
      for (int o = 0; o < 10; ++o) ppv[nf][o] = 0.f;
#pragma unroll
    for (int mf = 0; mf < 4; ++mf)
#pragma unroll
      for (int r = 0; r < 4; ++r) {
        const int jl = mf * 16 + g4 + r;       // D row = (lane>>4)*4 + reg
        const float e1v = e1l[jl];
        float w2s[10];
#pragma unroll
        for (int o = 0; o < 10; ++o)
          w2s[o] = fmaf(sf, e2l[jl * 10 + o], w2l[jl * 10 + o]);
#pragma unroll
        for (int nf = 0; nf < 4; ++nf) {
          const float bs = base[(size_t)(j0 + jl) * 256 + bw + nf * 16 + lm];
          const float h = fmaxf(fmaf(sf, acc[mf][nf][r] + e1v, bs), 0.f);
#pragma unroll
          for (int o = 0; o < 10; ++o) ppv[nf][o] = fmaf(h, w2s[o], ppv[nf][o]);
        }
      }
    // sum the 4 row-groups (lane bits 4,5); wave covers all 64 j
#pragma unroll
    for (int nf = 0; nf < 4; ++nf)
#pragma unroll
      for (int o = 0; o < 10; ++o) {
        float v = ppv[nf][o];
        v += __shfl_xor(v, 16, 64);
        v += __shfl_xor(v, 32, 64);
        ppv[nf][o] = v;
      }
    if (lane < 16) {
#pragma unroll
      for (int nf = 0; nf < 4; ++nf) {
        const int bl = bw + nf * 16 + lm;
        const size_t u0 = ((((size_t)p * 2 + s) * 32 + jt) * 256 + bl) * 5;
        ppu[u0 + 0] = packh(ppv[nf][0], ppv[nf][1]);
        ppu[u0 + 1] = packh(ppv[nf][2], ppv[nf][3]);
        ppu[u0 + 2] = packh(ppv[nf][4], ppv[nf][5]);
        ppu[u0 + 3] = packh(ppv[nf][6], ppv[nf][7]);
        ppu[u0 + 4] = packh(ppv[nf][8], ppv[nf][9]);
      }
    }
  }
}

// ---------------- k_loss: 80 losses ----------------
__global__ __launch_bounds__(256) void k_loss(const unsigned* __restrict__ ppu,
                                              const float* __restrict__ y,
                                              const float* __restrict__ b2,
                                              const float* __restrict__ noise,
                                              float* __restrict__ loss) {
  const int b = threadIdx.x;
  const int p = blockIdx.x >> 1, s = blockIdx.x & 1;
  const float sf = s ? -0.1f : 0.1f;
  const size_t pN = (size_t)p * NPLL;
  float pred[10];
#pragma unroll
  for (int o = 0; o < 10; ++o) pred[o] = b2[o] + sf * noise[pN + S3_ + o];
  for (int jt = 0; jt < 32; ++jt) {
    const size_t u0 = ((((size_t)p * 2 + s) * 32 + jt) * 256 + b) * 5;
#pragma unroll
    for (int q = 0; q < 5; ++q) {
      union { unsigned u; f16 h[2]; } w;
      w.u = ppu[u0 + q];
      pred[2 * q]     += (float)w.h[0];
      pred[2 * q + 1] += (float)w.h[1];
    }
  }
  float e = 0.f;
#pragma unroll
  for (int o = 0; o < 10; ++o) {
    float d = pred[o] - y[b * 10 + o];
    e += d * d;
  }
  __shared__ float red[256];
  red[b] = e;
  __syncthreads();
  for (int st = 128; st > 0; st >>= 1) {
    if (b < st) red[b] += red[b + st];
    __syncthreads();
  }
  if (b == 0) loss[blockIdx.x] = red[0] * (1.0f / 2560.0f);
}

// ---------------- k_rank: stable centered ranks -> pair coefficients --------
__global__ void k_rank(const float* __restrict__ loss, float* __restrict__ g) {
  __shared__ float ls[80];
  __shared__ float rk[80];
  const int t = threadIdx.x;
  if (t < 80) ls[t] = loss[t];
  __syncthreads();
  if (t < 80) {
    float li = ls[t];
    int r = 0;
    for (int j = 0; j < 80; ++j) {
      float lj = ls[j];
      r += (lj < li) || (lj == li && j < t);  // stable tie-break = argsort
    }
    rk[t] = (float)r;
  }
  __syncthreads();
  if (t < 40) g[t] = (rk[2 * t] - rk[2 * t + 1]) * (1.0f / (79.0f * 40.0f));
}

// ---------------- k_grad: out[k] = sum_p noise[p][k] * g[p] -----------------
__global__ __launch_bounds__(256) void k_grad(const float* __restrict__ noise,
                                              const float* __restrict__ g,
                                              float* __restrict__ out) {
  __shared__ float gg[40];
  const int t = threadIdx.x;
  if (t < 40) gg[t] = g[t];
  __syncthreads();
  const long long NH = NPLL / 2;
  long long idx = (long long)blockIdx.x * 256 + t;
  if (idx >= NH) return;
  float2 a = make_float2(0.f, 0.f);
#pragma unroll 8
  for (int p = 0; p < 40; ++p) {
    float2 v = *(const float2*)&noise[(size_t)p * NPLL + idx * 2];
    a.x += v.x * gg[p];
    a.y += v.y * gg[p];
  }
  *(float2*)&out[idx * 2] = a;
}

extern "C" void kernel_launch(void* const* d_in, const int* in_sizes, int n_in,
                              void* d_out, int out_size, void* d_ws, size_t ws_size,
                              hipStream_t stream) {
  const float* x     = (const float*)d_in[0];
  const float* y     = (const float*)d_in[1];
  const float* W1    = (const float*)d_in[2];
  const float* b1    = (const float*)d_in[3];
  const float* W2    = (const float*)d_in[4];
  const float* b2    = (const float*)d_in[5];
  const float* noise = (const float*)d_in[6];
  float* out  = (float*)d_out;
  float* ws   = (float*)d_ws;   // ~16.25 MB used
  float* base = ws;
  unsigned* ppu = (unsigned*)(ws + WS_PP);
  float* loss = ws + WS_LOSS;
  float* g    = ws + WS_G;
  f16* xs = (f16*)(ws + WS_XS);

  k_xsplit<<<128, 256, 0, stream>>>(x, xs);
  k_base<<<dim3(32, 8), 256, 0, stream>>>(x, W1, b1, base);
  k_big<<<dim3(32, 40), 256, 0, stream>>>(xs, noise, W2, base, ppu);
  k_loss<<<80, 256, 0, stream>>>(ppu, y, b2, noise, loss);
  k_rank<<<1, 128, 0, stream>>>(loss, g);
  k_grad<<<4141, 256, 0, stream>>>(noise, g, out);
}

// Round 8
// 549.742 us; speedup vs baseline: 1.4682x; 1.4682x over previous
//
#include <hip/hip_runtime.h>

// ES gradient for 2-layer MLP (D_IN=1024, HID=2048, D_OUT=10, POP=40, STD=0.1).
// k_xsplit (x -> fragment-order split-f16 global layout) -> k_base (fp32) ->
// k_big (split-f16 MFMA x@E1; E-only swizzled LDS; B-frags direct, coalesced)
// -> k_loss -> k_rank -> k_grad.
// Losses matter only through RANKS (gaps ~1e-2); split-f16 err ~1e-5 => safe.

#define NPLL 2119690LL          // N_PARAMS
#define S1_  2097152            // W1 end
#define S2_  2099200            // b1 end
#define S3_  2119680            // W2 end

// ws layout (f32 units):
//   base : [0, 524288)            base[j][b]  f32
//   ppu  : [524288, 3801088)      f16-packed [40][2][32 jt][256 b][5 dw]
//   loss : [3801088, 3801168)
//   g    : [3801168, 3801208)
//   xf   : [3801216, +262144)     f16 frag-order [32 kt][16 bblk][2 hl][4 qh][16 lm][8]
#define WS_PP   524288
#define WS_LOSS 3801088
#define WS_G    3801168
#define WS_XF   3801216

typedef _Float16 f16;
typedef __fp16   fp16x2 __attribute__((ext_vector_type(2)));
typedef _Float16 f16x2t __attribute__((ext_vector_type(2)));
typedef _Float16 f16x8 __attribute__((ext_vector_type(8)));
typedef float    f32x4 __attribute__((ext_vector_type(4)));

__device__ __forceinline__ unsigned pk2r(float a, float b, float& ra, float& rb) {
  fp16x2 h = __builtin_amdgcn_cvt_pkrtz(a, b);   // v_cvt_pkrtz_f16_f32
  ra = a - (float)h[0];
  rb = b - (float)h[1];
  return __builtin_bit_cast(unsigned, h);
}
__device__ __forceinline__ unsigned pk2(float a, float b) {
  fp16x2 h = __builtin_amdgcn_cvt_pkrtz(a, b);
  return __builtin_bit_cast(unsigned, h);
}
__device__ __forceinline__ unsigned packh(float a, float b) {  // RTN, no union
  f16x2t v = {(f16)a, (f16)b};
  return __builtin_bit_cast(unsigned, v);
}
__device__ __forceinline__ float unpk_lo(unsigned u) {
  return (float)__builtin_bit_cast(f16, (unsigned short)(u & 0xffffu));
}
__device__ __forceinline__ float unpk_hi(unsigned u) {
  return (float)__builtin_bit_cast(f16, (unsigned short)(u >> 16));
}

// ---------------- k_xsplit: x -> fragment-order split-f16 -------------------
// Element for (kt,bblk,hl,qh,lm,e): x[b=bblk*16+lm][k=kt*32+qh*8+e], hl=0 hi / 1 lo.
// A wave's B-frag load (fixed kt,bblk,hl; lanes (qh,lm)) is 1 KB contiguous.
__global__ __launch_bounds__(256) void k_xsplit(const float* __restrict__ x,
                                                f16* __restrict__ xf) {
  const int idx = blockIdx.x * 256 + threadIdx.x;  // 32768
  const int b  = idx >> 7;           // 0..255
  const int k8 = idx & 127;          // k-octet index
  const int kt = k8 >> 2, qh = k8 & 3;
  const int bblk = b >> 4, lm = b & 15;
  float4 a0 = *(const float4*)&x[(size_t)b * 1024 + k8 * 8];
  float4 a1 = *(const float4*)&x[(size_t)b * 1024 + k8 * 8 + 4];
  float v[8] = {a0.x, a0.y, a0.z, a0.w, a1.x, a1.y, a1.z, a1.w};
  float r[8];
  uint4 H, L;
  H.x = pk2r(v[0], v[1], r[0], r[1]);
  H.y = pk2r(v[2], v[3], r[2], r[3]);
  H.z = pk2r(v[4], v[5], r[4], r[5]);
  H.w = pk2r(v[6], v[7], r[6], r[7]);
  L.x = pk2(r[0], r[1]); L.y = pk2(r[2], r[3]);
  L.z = pk2(r[4], r[5]); L.w = pk2(r[6], r[7]);
  const size_t hi = ((((size_t)(kt * 16 + bblk) * 2 + 0) * 4 + qh) * 16 + lm) * 8;
  const size_t lo = ((((size_t)(kt * 16 + bblk) * 2 + 1) * 4 + qh) * 16 + lm) * 8;
  *(uint4*)&xf[hi] = H;
  *(uint4*)&xf[lo] = L;
}

// ---------------- k_base: base[j][b] = (x @ W1)[b][j] + b1[j] (fp32) --------
__global__ __launch_bounds__(256) void k_base(const float* __restrict__ x,
                                              const float* __restrict__ W1,
                                              const float* __restrict__ b1,
                                              float* __restrict__ base) {
  constexpr int STR = 72;
  __shared__ float xsm[32 * STR];
  __shared__ float es[32 * STR];
  const int t  = threadIdx.x;
  const int j0 = blockIdx.x * 64;
  const int b0 = blockIdx.y * 32;
  const int tj = t & 15;
  const int tb = t >> 4;
  float acc[4][2] = {};
  for (int k0 = 0; k0 < 1024; k0 += 32) {
    __syncthreads();
    {
      int bb = t >> 3, kq = t & 7;
      float4 v = *(const float4*)&x[(size_t)(b0 + bb) * 1024 + k0 + kq * 4];
      int kb = kq * 4;
      xsm[(kb + 0) * STR + bb] = v.x;
      xsm[(kb + 1) * STR + bb] = v.y;
      xsm[(kb + 2) * STR + bb] = v.z;
      xsm[(kb + 3) * STR + bb] = v.w;
    }
#pragma unroll
    for (int r = 0; r < 2; ++r) {
      int idx = t + r * 256;
      int k = idx >> 4, jq = idx & 15, col = jq * 4;
      float4 v = *(const float4*)&W1[(size_t)(k0 + k) * 2048 + j0 + col];
      *(float4*)&es[k * STR + col + 4 * (col >> 5)] = v;
    }
    __syncthreads();
#pragma unroll 8
    for (int k = 0; k < 32; ++k) {
      const int ce = tj * 4;
      float4 e = *(const float4*)&es[k * STR + ce + 4 * (ce >> 5)];
      float2 a = *(const float2*)&xsm[k * STR + tb * 2];
      acc[0][0] += e.x * a.x; acc[0][1] += e.x * a.y;
      acc[1][0] += e.y * a.x; acc[1][1] += e.y * a.y;
      acc[2][0] += e.z * a.x; acc[2][1] += e.z * a.y;
      acc[3][0] += e.w * a.x; acc[3][1] += e.w * a.y;
    }
  }
#pragma unroll
  for (int jj = 0; jj < 4; ++jj) {
    int j = j0 + tj * 4 + jj;
    float bv = b1[j];
    float2 o = make_float2(acc[jj][0] + bv, acc[jj][1] + bv);
    *(float2*)&base[(size_t)j * 256 + b0 + tb * 2] = o;
  }
}

// ---------------- k_big: split-f16 MFMA x@E1 + fused epilogue ---------------
// grid (32 jt, 40 p), 256 threads = 4 waves; block tile j64 x b256; each wave
// owns a 64-wide b-slice and all 64 j rows. E-only LDS (8 KB, XOR-swizzled).
__global__ __launch_bounds__(256, 2) void k_big(const f16* __restrict__ xf,
                                                const float* __restrict__ noise,
                                                const float* __restrict__ W2,
                                                const float* __restrict__ base,
                                                unsigned* __restrict__ ppu) {
  __shared__ __align__(16) char smem[8192];
  f16* eA = (f16*)smem;            // [64 j][8 chunks of 8, XOR-swizzled]
  float* w2l = (float*)smem;       // epilogue overlay (5.4 KB <= 8 KB)
  float* e2l = w2l + 640;
  float* e1l = e2l + 640;

  const int t    = threadIdx.x;
  const int jt   = blockIdx.x, p = blockIdx.y;
  const int j0   = jt * 64;
  const int wave = t >> 6, lane = t & 63;
  const int lm   = lane & 15, qh = lane >> 4;   // frag row / k-octet
  const int g4   = qh * 4;
  const int bw   = wave * 64;
  const size_t pN = (size_t)p * NPLL;
  const int srow = t & 63, sq = t >> 6;         // staging role
  const int sswz = (srow & 7) << 3;

  float ve[8];
  f32x4 acc[4][4];
#pragma unroll
  for (int a = 0; a < 4; ++a)
#pragma unroll
    for (int b = 0; b < 4; ++b) acc[a][b] = (f32x4){0.f, 0.f, 0.f, 0.f};

  const float* Ebase = noise + pN + (size_t)(sq * 8) * 2048 + j0 + srow;
  // A-frag LDS byte offsets (compile-time per mf after hoisting)
  const int aswz = (lm & 7) << 3;

  // prologue: E loads for ks=0
#pragma unroll
  for (int d = 0; d < 8; ++d) ve[d] = Ebase[(size_t)d * 2048];

  for (int ks = 0; ks < 32; ++ks) {
    __syncthreads();   // previous MFMA reads done; eA free
    {  // stage E: convert 8 f32 -> hi/lo 16B, swizzled write
      float r0, r1, r2, r3, r4, r5, r6, r7;
      uint4 H, L;
      H.x = pk2r(ve[0], ve[1], r0, r1);
      H.y = pk2r(ve[2], ve[3], r2, r3);
      H.z = pk2r(ve[4], ve[5], r4, r5);
      H.w = pk2r(ve[6], ve[7], r6, r7);
      *(uint4*)&eA[srow * 64 + ((sq * 8) ^ sswz)] = H;
      L.x = pk2(r0, r1); L.y = pk2(r2, r3);
      L.z = pk2(r4, r5); L.w = pk2(r6, r7);
      *(uint4*)&eA[srow * 64 + (((sq + 4) * 8) ^ sswz)] = L;
    }
    // prefetch next-step E into regs (latency hidden under MFMA phase)
    if (ks < 31) {
      const float* En = Ebase + (size_t)(ks + 1) * 32 * 2048;
#pragma unroll
      for (int d = 0; d < 8; ++d) ve[d] = En[(size_t)d * 2048];
    }
    __syncthreads();   // eA tile ready
    // B fragments direct from global, fragment-order => 1 KB coalesced/load
    const f16* xk = xf + (size_t)ks * 16384;
    f16x8 Bh[4], Bl[4];
#pragma unroll
    for (int nf = 0; nf < 4; ++nf) {
      const int bblk = wave * 4 + nf;
      const size_t fo = (((size_t)bblk * 2) * 4 + qh) * 128 + lm * 8;
      Bh[nf] = *(const f16x8*)&xk[fo];
      Bl[nf] = *(const f16x8*)&xk[fo + 512];
    }
#pragma unroll
    for (int mf = 0; mf < 4; ++mf) {
      const int ra = mf * 16 + lm;
      f16x8 Ah = *(const f16x8*)&eA[ra * 64 + ((qh * 8) ^ aswz)];
      f16x8 Al = *(const f16x8*)&eA[ra * 64 + (((qh + 4) * 8) ^ aswz)];
#pragma unroll
      for (int nf = 0; nf < 4; ++nf) {
        acc[mf][nf] = __builtin_amdgcn_mfma_f32_16x16x32_f16(Ah, Bh[nf], acc[mf][nf], 0, 0, 0);
        acc[mf][nf] = __builtin_amdgcn_mfma_f32_16x16x32_f16(Ah, Bl[nf], acc[mf][nf], 0, 0, 0);
        acc[mf][nf] = __builtin_amdgcn_mfma_f32_16x16x32_f16(Al, Bh[nf], acc[mf][nf], 0, 0, 0);
      }
    }
  }

  // ---- epilogue: tables overlay dead eA region ----
  __syncthreads();
  for (int i = t; i < 640; i += 256) {
    w2l[i] = W2[j0 * 10 + i];
    e2l[i] = noise[pN + S2_ + (size_t)j0 * 10 + i];
  }
  if (t < 64) e1l[t] = noise[pN + S1_ + j0 + t];
  __syncthreads();

#pragma unroll 1
  for (int s = 0; s < 2; ++s) {
    const float sf = s ? -0.1f : 0.1f;
    float ppv[4][10];
#pragma unroll
    for (int nf = 0; nf < 4; ++nf)
#pragma unroll
      for (int o = 0; o < 10; ++o) ppv[nf][o] = 0.f;
#pragma unroll
    for (int mf = 0; mf < 4; ++mf)
#pragma unroll
      for (int r = 0; r < 4; ++r) {
        const int jl = mf * 16 + g4 + r;       // D row = (lane>>4)*4 + reg
        const float e1v = e1l[jl];
        float w2s[10];
#pragma unroll
        for (int o = 0; o < 10; ++o)
          w2s[o] = fmaf(sf, e2l[jl * 10 + o], w2l[jl * 10 + o]);
#pragma unroll
        for (int nf = 0; nf < 4; ++nf) {
          const float bs = base[(size_t)(j0 + jl) * 256 + bw + nf * 16 + lm];
          const float h = fmaxf(fmaf(sf, acc[mf][nf][r] + e1v, bs), 0.f);
#pragma unroll
          for (int o = 0; o < 10; ++o) ppv[nf][o] = fmaf(h, w2s[o], ppv[nf][o]);
        }
      }
    // sum the 4 row-groups (lane bits 4,5); wave covers all 64 j
#pragma unroll
    for (int nf = 0; nf < 4; ++nf)
#pragma unroll
      for (int o = 0; o < 10; ++o) {
        float v = ppv[nf][o];
        v += __shfl_xor(v, 16, 64);
        v += __shfl_xor(v, 32, 64);
        ppv[nf][o] = v;
      }
    if (lane < 16) {
#pragma unroll
      for (int nf = 0; nf < 4; ++nf) {
        const int bl = bw + nf * 16 + lm;
        const size_t u0 = ((((size_t)p * 2 + s) * 32 + jt) * 256 + bl) * 5;
        ppu[u0 + 0] = packh(ppv[nf][0], ppv[nf][1]);
        ppu[u0 + 1] = packh(ppv[nf][2], ppv[nf][3]);
        ppu[u0 + 2] = packh(ppv[nf][4], ppv[nf][5]);
        ppu[u0 + 3] = packh(ppv[nf][6], ppv[nf][7]);
        ppu[u0 + 4] = packh(ppv[nf][8], ppv[nf][9]);
      }
    }
  }
}

// ---------------- k_loss: 80 losses ----------------
__global__ __launch_bounds__(256) void k_loss(const unsigned* __restrict__ ppu,
                                              const float* __restrict__ y,
                                              const float* __restrict__ b2,
                                              const float* __restrict__ noise,
                                              float* __restrict__ loss) {
  const int b = threadIdx.x;
  const int p = blockIdx.x >> 1, s = blockIdx.x & 1;
  const float sf = s ? -0.1f : 0.1f;
  const size_t pN = (size_t)p * NPLL;
  float pred[10];
#pragma unroll
  for (int o = 0; o < 10; ++o) pred[o] = b2[o] + sf * noise[pN + S3_ + o];
  for (int jt = 0; jt < 32; ++jt) {
    const size_t u0 = ((((size_t)p * 2 + s) * 32 + jt) * 256 + b) * 5;
#pragma unroll
    for (int q = 0; q < 5; ++q) {
      unsigned u = ppu[u0 + q];
      pred[2 * q]     += unpk_lo(u);
      pred[2 * q + 1] += unpk_hi(u);
    }
  }
  float e = 0.f;
#pragma unroll
  for (int o = 0; o < 10; ++o) {
    float d = pred[o] - y[b * 10 + o];
    e += d * d;
  }
  __shared__ float red[256];
  red[b] = e;
  __syncthreads();
  for (int st = 128; st > 0; st >>= 1) {
    if (b < st) red[b] += red[b + st];
    __syncthreads();
  }
  if (b == 0) loss[blockIdx.x] = red[0] * (1.0f / 2560.0f);
}

// ---------------- k_rank: stable centered ranks -> pair coefficients --------
__global__ void k_rank(const float* __restrict__ loss, float* __restrict__ g) {
  __shared__ float ls[80];
  __shared__ float rk[80];
  const int t = threadIdx.x;
  if (t < 80) ls[t] = loss[t];
  __syncthreads();
  if (t < 80) {
    float li = ls[t];
    int r = 0;
    for (int j = 0; j < 80; ++j) {
      float lj = ls[j];
      r += (lj < li) || (lj == li && j < t);  // stable tie-break = argsort
    }
    rk[t] = (float)r;
  }
  __syncthreads();
  if (t < 40) g[t] = (rk[2 * t] - rk[2 * t + 1]) * (1.0f / (79.0f * 40.0f));
}

// ---------------- k_grad: out[k] = sum_p noise[p][k] * g[p] -----------------
__global__ __launch_bounds__(256) void k_grad(const float* __restrict__ noise,
                                              const float* __restrict__ g,
                                              float* __restrict__ out) {
  __shared__ float gg[40];
  const int t = threadIdx.x;
  if (t < 40) gg[t] = g[t];
  __syncthreads();
  const long long NH = NPLL / 2;
  long long idx = (long long)blockIdx.x * 256 + t;
  if (idx >= NH) return;
  float2 a = make_float2(0.f, 0.f);
#pragma unroll 8
  for (int p = 0; p < 40; ++p) {
    float2 v = *(const float2*)&noise[(size_t)p * NPLL + idx * 2];
    a.x += v.x * gg[p];
    a.y += v.y * gg[p];
  }
  *(float2*)&out[idx * 2] = a;
}

extern "C" void kernel_launch(void* const* d_in, const int* in_sizes, int n_in,
                              void* d_out, int out_size, void* d_ws, size_t ws_size,
                              hipStream_t stream) {
  const float* x     = (const float*)d_in[0];
  const float* y     = (const float*)d_in[1];
  const float* W1    = (const float*)d_in[2];
  const float* b1    = (const float*)d_in[3];
  const float* W2    = (const float*)d_in[4];
  const float* b2    = (const float*)d_in[5];
  const float* noise = (const float*)d_in[6];
  float* out  = (float*)d_out;
  float* ws   = (float*)d_ws;   // ~16.25 MB used
  float* base = ws;
  unsigned* ppu = (unsigned*)(ws + WS_PP);
  float* loss = ws + WS_LOSS;
  float* g    = ws + WS_G;
  f16* xf = (f16*)(ws + WS_XF);

  k_xsplit<<<128, 256, 0, stream>>>(x, xf);
  k_base<<<dim3(32, 8), 256, 0, stream>>>(x, W1, b1, base);
  k_big<<<dim3(32, 40), 256, 0, stream>>>(xf, noise, W2, base, ppu);
  k_loss<<<80, 256, 0, stream>>>(ppu, y, b2, noise, loss);
  k_rank<<<1, 128, 0, stream>>>(loss, g);
  k_grad<<<4141, 256, 0, stream>>>(noise, g, out);
}

// Round 9
// 368.515 us; speedup vs baseline: 2.1902x; 1.4918x over previous
//
#include <hip/hip_runtime.h>

// ES gradient for 2-layer MLP (D_IN=1024, HID=2048, D_OUT=10, POP=40, STD=0.1).
// k_xsplit (x -> fragment-order split-f16 global layout) -> k_base (fp32) ->
// k_big (split-f16 MFMA x@E1; E-only swizzled LDS; B-frags direct, coalesced)
// -> k_loss -> k_rank -> k_grad.
// Losses matter only through RANKS (gaps ~1e-2); split-f16 err ~1e-5 => safe.
// NOTE: no 2nd __launch_bounds__ arg on k_big — hipcc caps VGPR at 256/arg
// (measured R5/R7/R8) and silently spills the k-loop (deterministic 374-973 MB
// HBM writes). Allocator must be free to take ~160 VGPRs.

#define NPLL 2119690LL          // N_PARAMS
#define S1_  2097152            // W1 end
#define S2_  2099200            // b1 end
#define S3_  2119680            // W2 end

// ws layout (f32 units):
//   base : [0, 524288)            base[j][b]  f32
//   ppu  : [524288, 3801088)      f16-packed [40][2][32 jt][256 b][5 dw]
//   loss : [3801088, 3801168)
//   g    : [3801168, 3801208)
//   xf   : [3801216, +262144)     f16 frag-order [32 kt][16 bblk][2 hl][4 qh][16 lm][8]
#define WS_PP   524288
#define WS_LOSS 3801088
#define WS_G    3801168
#define WS_XF   3801216

typedef _Float16 f16;
typedef __fp16   fp16x2 __attribute__((ext_vector_type(2)));
typedef _Float16 f16x2t __attribute__((ext_vector_type(2)));
typedef _Float16 f16x8 __attribute__((ext_vector_type(8)));
typedef float    f32x4 __attribute__((ext_vector_type(4)));

__device__ __forceinline__ unsigned pk2r(float a, float b, float& ra, float& rb) {
  fp16x2 h = __builtin_amdgcn_cvt_pkrtz(a, b);   // v_cvt_pkrtz_f16_f32
  ra = a - (float)h[0];
  rb = b - (float)h[1];
  return __builtin_bit_cast(unsigned, h);
}
__device__ __forceinline__ unsigned pk2(float a, float b) {
  fp16x2 h = __builtin_amdgcn_cvt_pkrtz(a, b);
  return __builtin_bit_cast(unsigned, h);
}
__device__ __forceinline__ unsigned packh(float a, float b) {  // RTN, no union
  f16x2t v = {(f16)a, (f16)b};
  return __builtin_bit_cast(unsigned, v);
}
__device__ __forceinline__ float unpk_lo(unsigned u) {
  return (float)__builtin_bit_cast(f16, (unsigned short)(u & 0xffffu));
}
__device__ __forceinline__ float unpk_hi(unsigned u) {
  return (float)__builtin_bit_cast(f16, (unsigned short)(u >> 16));
}

// ---------------- k_xsplit: x -> fragment-order split-f16 -------------------
// Element for (kt,bblk,hl,qh,lm,e): x[b=bblk*16+lm][k=kt*32+qh*8+e], hl=0 hi / 1 lo.
// A wave's B-frag load (fixed kt,bblk,hl; lanes (qh,lm)) is 1 KB contiguous.
__global__ __launch_bounds__(256) void k_xsplit(const float* __restrict__ x,
                                                f16* __restrict__ xf) {
  const int idx = blockIdx.x * 256 + threadIdx.x;  // 32768
  const int b  = idx >> 7;           // 0..255
  const int k8 = idx & 127;          // k-octet index
  const int kt = k8 >> 2, qh = k8 & 3;
  const int bblk = b >> 4, lm = b & 15;
  float4 a0 = *(const float4*)&x[(size_t)b * 1024 + k8 * 8];
  float4 a1 = *(const float4*)&x[(size_t)b * 1024 + k8 * 8 + 4];
  float v[8] = {a0.x, a0.y, a0.z, a0.w, a1.x, a1.y, a1.z, a1.w};
  float r[8];
  uint4 H, L;
  H.x = pk2r(v[0], v[1], r[0], r[1]);
  H.y = pk2r(v[2], v[3], r[2], r[3]);
  H.z = pk2r(v[4], v[5], r[4], r[5]);
  H.w = pk2r(v[6], v[7], r[6], r[7]);
  L.x = pk2(r[0], r[1]); L.y = pk2(r[2], r[3]);
  L.z = pk2(r[4], r[5]); L.w = pk2(r[6], r[7]);
  const size_t hi = ((((size_t)(kt * 16 + bblk) * 2 + 0) * 4 + qh) * 16 + lm) * 8;
  const size_t lo = ((((size_t)(kt * 16 + bblk) * 2 + 1) * 4 + qh) * 16 + lm) * 8;
  *(uint4*)&xf[hi] = H;
  *(uint4*)&xf[lo] = L;
}

// ---------------- k_base: base[j][b] = (x @ W1)[b][j] + b1[j] (fp32) --------
__global__ __launch_bounds__(256) void k_base(const float* __restrict__ x,
                                              const float* __restrict__ W1,
                                              const float* __restrict__ b1,
                                              float* __restrict__ base) {
  constexpr int STR = 72;
  __shared__ float xsm[32 * STR];
  __shared__ float es[32 * STR];
  const int t  = threadIdx.x;
  const int j0 = blockIdx.x * 64;
  const int b0 = blockIdx.y * 32;
  const int tj = t & 15;
  const int tb = t >> 4;
  float acc[4][2] = {};
  for (int k0 = 0; k0 < 1024; k0 += 32) {
    __syncthreads();
    {
      int bb = t >> 3, kq = t & 7;
      float4 v = *(const float4*)&x[(size_t)(b0 + bb) * 1024 + k0 + kq * 4];
      int kb = kq * 4;
      xsm[(kb + 0) * STR + bb] = v.x;
      xsm[(kb + 1) * STR + bb] = v.y;
      xsm[(kb + 2) * STR + bb] = v.z;
      xsm[(kb + 3) * STR + bb] = v.w;
    }
#pragma unroll
    for (int r = 0; r < 2; ++r) {
      int idx = t + r * 256;
      int k = idx >> 4, jq = idx & 15, col = jq * 4;
      float4 v = *(const float4*)&W1[(size_t)(k0 + k) * 2048 + j0 + col];
      *(float4*)&es[k * STR + col + 4 * (col >> 5)] = v;
    }
    __syncthreads();
#pragma unroll 8
    for (int k = 0; k < 32; ++k) {
      const int ce = tj * 4;
      float4 e = *(const float4*)&es[k * STR + ce + 4 * (ce >> 5)];
      float2 a = *(const float2*)&xsm[k * STR + tb * 2];
      acc[0][0] += e.x * a.x; acc[0][1] += e.x * a.y;
      acc[1][0] += e.y * a.x; acc[1][1] += e.y * a.y;
      acc[2][0] += e.z * a.x; acc[2][1] += e.z * a.y;
      acc[3][0] += e.w * a.x; acc[3][1] += e.w * a.y;
    }
  }
#pragma unroll
  for (int jj = 0; jj < 4; ++jj) {
    int j = j0 + tj * 4 + jj;
    float bv = b1[j];
    float2 o = make_float2(acc[jj][0] + bv, acc[jj][1] + bv);
    *(float2*)&base[(size_t)j * 256 + b0 + tb * 2] = o;
  }
}

// ---------------- k_big: split-f16 MFMA x@E1 + fused epilogue ---------------
// grid (32 jt, 40 p), 256 threads = 4 waves; block tile j64 x b256; each wave
// owns a 64-wide b-slice and all 64 j rows. E-only LDS (8 KB, XOR-swizzled).
__global__ __launch_bounds__(256) void k_big(const f16* __restrict__ xf,
                                             const float* __restrict__ noise,
                                             const float* __restrict__ W2,
                                             const float* __restrict__ base,
                                             unsigned* __restrict__ ppu) {
  __shared__ __align__(16) char smem[8192];
  f16* eA = (f16*)smem;            // [64 j][8 chunks of 8, XOR-swizzled]
  float* w2l = (float*)smem;       // epilogue overlay (5.4 KB <= 8 KB)
  float* e2l = w2l + 640;
  float* e1l = e2l + 640;

  const int t    = threadIdx.x;
  const int jt   = blockIdx.x, p = blockIdx.y;
  const int j0   = jt * 64;
  const int wave = t >> 6, lane = t & 63;
  const int lm   = lane & 15, qh = lane >> 4;   // frag row / k-octet
  const int g4   = qh * 4;
  const int bw   = wave * 64;
  const size_t pN = (size_t)p * NPLL;
  const int srow = t & 63, sq = t >> 6;         // staging role
  const int sswz = (srow & 7) << 3;

  float ve[8];
  f32x4 acc[4][4];
#pragma unroll
  for (int a = 0; a < 4; ++a)
#pragma unroll
    for (int b = 0; b < 4; ++b) acc[a][b] = (f32x4){0.f, 0.f, 0.f, 0.f};

  const float* Ebase = noise + pN + (size_t)(sq * 8) * 2048 + j0 + srow;
  const int aswz = (lm & 7) << 3;

  // prologue: E loads for ks=0
#pragma unroll
  for (int d = 0; d < 8; ++d) ve[d] = Ebase[(size_t)d * 2048];

  for (int ks = 0; ks < 32; ++ks) {
    __syncthreads();   // previous MFMA reads done; eA free
    {  // stage E: convert 8 f32 -> hi/lo 16B, swizzled write
      float r0, r1, r2, r3, r4, r5, r6, r7;
      uint4 H, L;
      H.x = pk2r(ve[0], ve[1], r0, r1);
      H.y = pk2r(ve[2], ve[3], r2, r3);
      H.z = pk2r(ve[4], ve[5], r4, r5);
      H.w = pk2r(ve[6], ve[7], r6, r7);
      *(uint4*)&eA[srow * 64 + ((sq * 8) ^ sswz)] = H;
      L.x = pk2(r0, r1); L.y = pk2(r2, r3);
      L.z = pk2(r4, r5); L.w = pk2(r6, r7);
      *(uint4*)&eA[srow * 64 + (((sq + 4) * 8) ^ sswz)] = L;
    }
    // B fragments for THIS step: issue早 so L2 latency hides under barrier;
    // fragment-order => each load is 1 KB contiguous per wave
    const f16* xk = xf + (size_t)ks * 16384;
    f16x8 Bh[4], Bl[4];
#pragma unroll
    for (int nf = 0; nf < 4; ++nf) {
      const int bblk = wave * 4 + nf;
      const size_t fo = (((size_t)bblk * 2) * 4 + qh) * 128 + lm * 8;
      Bh[nf] = *(const f16x8*)&xk[fo];
      Bl[nf] = *(const f16x8*)&xk[fo + 512];
    }
    // prefetch next-step E into regs (completes during MFMA phase)
    if (ks < 31) {
      const float* En = Ebase + (size_t)(ks + 1) * 32 * 2048;
#pragma unroll
      for (int d = 0; d < 8; ++d) ve[d] = En[(size_t)d * 2048];
    }
    __syncthreads();   // eA tile ready
#pragma unroll
    for (int mf = 0; mf < 4; ++mf) {
      const int ra = mf * 16 + lm;
      f16x8 Ah = *(const f16x8*)&eA[ra * 64 + ((qh * 8) ^ aswz)];
      f16x8 Al = *(const f16x8*)&eA[ra * 64 + (((qh + 4) * 8) ^ aswz)];
#pragma unroll
      for (int nf = 0; nf < 4; ++nf) {
        acc[mf][nf] = __builtin_amdgcn_mfma_f32_16x16x32_f16(Ah, Bh[nf], acc[mf][nf], 0, 0, 0);
        acc[mf][nf] = __builtin_amdgcn_mfma_f32_16x16x32_f16(Ah, Bl[nf], acc[mf][nf], 0, 0, 0);
        acc[mf][nf] = __builtin_amdgcn_mfma_f32_16x16x32_f16(Al, Bh[nf], acc[mf][nf], 0, 0, 0);
      }
    }
  }

  // ---- epilogue: tables overlay dead eA region ----
  __syncthreads();
  for (int i = t; i < 640; i += 256) {
    w2l[i] = W2[j0 * 10 + i];
    e2l[i] = noise[pN + S2_ + (size_t)j0 * 10 + i];
  }
  if (t < 64) e1l[t] = noise[pN + S1_ + j0 + t];
  __syncthreads();

#pragma unroll 1
  for (int s = 0; s < 2; ++s) {
    const float sf = s ? -0.1f : 0.1f;
    float ppv[4][10];
#pragma unroll
    for (int nf = 0; nf < 4; ++nf)
#pragma unroll
      for (int o = 0; o < 10; ++o) ppv[nf][o] = 0.f;
#pragma unroll
    for (int mf = 0; mf < 4; ++mf)
#pragma unroll
      for (int r = 0; r < 4; ++r) {
        const int jl = mf * 16 + g4 + r;       // D row = (lane>>4)*4 + reg
        const float e1v = e1l[jl];
        float w2s[10];
#pragma unroll
        for (int o = 0; o < 10; ++o)
          w2s[o] = fmaf(sf, e2l[jl * 10 + o], w2l[jl * 10 + o]);
#pragma unroll
        for (int nf = 0; nf < 4; ++nf) {
          const float bs = base[(size_t)(j0 + jl) * 256 + bw + nf * 16 + lm];
          const float h = fmaxf(fmaf(sf, acc[mf][nf][r] + e1v, bs), 0.f);
#pragma unroll
          for (int o = 0; o < 10; ++o) ppv[nf][o] = fmaf(h, w2s[o], ppv[nf][o]);
        }
      }
    // sum the 4 row-groups (lane bits 4,5); wave covers all 64 j
#pragma unroll
    for (int nf = 0; nf < 4; ++nf)
#pragma unroll
      for (int o = 0; o < 10; ++o) {
        float v = ppv[nf][o];
        v += __shfl_xor(v, 16, 64);
        v += __shfl_xor(v, 32, 64);
        ppv[nf][o] = v;
      }
    if (lane < 16) {
#pragma unroll
      for (int nf = 0; nf < 4; ++nf) {
        const int bl = bw + nf * 16 + lm;
        const size_t u0 = ((((size_t)p * 2 + s) * 32 + jt) * 256 + bl) * 5;
        ppu[u0 + 0] = packh(ppv[nf][0], ppv[nf][1]);
        ppu[u0 + 1] = packh(ppv[nf][2], ppv[nf][3]);
        ppu[u0 + 2] = packh(ppv[nf][4], ppv[nf][5]);
        ppu[u0 + 3] = packh(ppv[nf][6], ppv[nf][7]);
        ppu[u0 + 4] = packh(ppv[nf][8], ppv[nf][9]);
      }
    }
  }
}

// ---------------- k_loss: 80 losses ----------------
__global__ __launch_bounds__(256) void k_loss(const unsigned* __restrict__ ppu,
                                              const float* __restrict__ y,
                                              const float* __restrict__ b2,
                                              const float* __restrict__ noise,
                                              float* __restrict__ loss) {
  const int b = threadIdx.x;
  const int p = blockIdx.x >> 1, s = blockIdx.x & 1;
  const float sf = s ? -0.1f : 0.1f;
  const size_t pN = (size_t)p * NPLL;
  float pred[10];
#pragma unroll
  for (int o = 0; o < 10; ++o) pred[o] = b2[o] + sf * noise[pN + S3_ + o];
  for (int jt = 0; jt < 32; ++jt) {
    const size_t u0 = ((((size_t)p * 2 + s) * 32 + jt) * 256 + b) * 5;
#pragma unroll
    for (int q = 0; q < 5; ++q) {
      unsigned u = ppu[u0 + q];
      pred[2 * q]     += unpk_lo(u);
      pred[2 * q + 1] += unpk_hi(u);
    }
  }
  float e = 0.f;
#pragma unroll
  for (int o = 0; o < 10; ++o) {
    float d = pred[o] - y[b * 10 + o];
    e += d * d;
  }
  __shared__ float red[256];
  red[b] = e;
  __syncthreads();
  for (int st = 128; st > 0; st >>= 1) {
    if (b < st) red[b] += red[b + st];
    __syncthreads();
  }
  if (b == 0) loss[blockIdx.x] = red[0] * (1.0f / 2560.0f);
}

// ---------------- k_rank: stable centered ranks -> pair coefficients --------
__global__ void k_rank(const float* __restrict__ loss, float* __restrict__ g) {
  __shared__ float ls[80];
  __shared__ float rk[80];
  const int t = threadIdx.x;
  if (t < 80) ls[t] = loss[t];
  __syncthreads();
  if (t < 80) {
    float li = ls[t];
    int r = 0;
    for (int j = 0; j < 80; ++j) {
      float lj = ls[j];
      r += (lj < li) || (lj == li && j < t);  // stable tie-break = argsort
    }
    rk[t] = (float)r;
  }
  __syncthreads();
  if (t < 40) g[t] = (rk[2 * t] - rk[2 * t + 1]) * (1.0f / (79.0f * 40.0f));
}

// ---------------- k_grad: out[k] = sum_p noise[p][k] * g[p] -----------------
__global__ __launch_bounds__(256) void k_grad(const float* __restrict__ noise,
                                              const float* __restrict__ g,
                                              float* __restrict__ out) {
  __shared__ float gg[40];
  const int t = threadIdx.x;
  if (t < 40) gg[t] = g[t];
  __syncthreads();
  const long long NH = NPLL / 2;
  long long idx = (long long)blockIdx.x * 256 + t;
  if (idx >= NH) return;
  float2 a = make_float2(0.f, 0.f);
#pragma unroll 8
  for (int p = 0; p < 40; ++p) {
    float2 v = *(const float2*)&noise[(size_t)p * NPLL + idx * 2];
    a.x += v.x * gg[p];
    a.y += v.y * gg[p];
  }
  *(float2*)&out[idx * 2] = a;
}

extern "C" void kernel_launch(void* const* d_in, const int* in_sizes, int n_in,
                              void* d_out, int out_size, void* d_ws, size_t ws_size,
                              hipStream_t stream) {
  const float* x     = (const float*)d_in[0];
  const float* y     = (const float*)d_in[1];
  const float* W1    = (const float*)d_in[2];
  const float* b1    = (const float*)d_in[3];
  const float* W2    = (const float*)d_in[4];
  const float* b2    = (const float*)d_in[5];
  const float* noise = (const float*)d_in[6];
  float* out  = (float*)d_out;
  float* ws   = (float*)d_ws;   // ~16.25 MB used
  float* base = ws;
  unsigned* ppu = (unsigned*)(ws + WS_PP);
  float* loss = ws + WS_LOSS;
  float* g    = ws + WS_G;
  f16* xf = (f16*)(ws + WS_XF);

  k_xsplit<<<128, 256, 0, stream>>>(x, xf);
  k_base<<<dim3(32, 8), 256, 0, stream>>>(x, W1, b1, base);
  k_big<<<dim3(32, 40), 256, 0, stream>>>(xf, noise, W2, base, ppu);
  k_loss<<<80, 256, 0, stream>>>(ppu, y, b2, noise, loss);
  k_rank<<<1, 128, 0, stream>>>(loss, g);
  k_grad<<<4141, 256, 0, stream>>>(noise, g, out);
}